// Round 1
// baseline (218.921 us; speedup 1.0000x reference)
//
#include <hip/hip_runtime.h>
#include <stdint.h>

// B=16, CIN=512, COUT=128, H=W=64
#define NB    16
#define CIN   512
#define COUT  128
#define HW    4096

using bf16x8  = __attribute__((ext_vector_type(8))) __bf16;
using floatx4 = __attribute__((ext_vector_type(4))) float;

// RNE float -> bf16 bits (proven in previous session)
__device__ __forceinline__ unsigned short f2bf_bits(float f) {
    union { float f; unsigned u; } v; v.f = f;
    return (unsigned short)((v.u + 0x7fffu + ((v.u >> 16) & 1u)) >> 16);
}

// ---------------------------------------------------------------------------
// Precompute mw[b][k8][m][j] = bf16(weight[m][k8*8+j] * style[b][k8*8+j])
// = the 16x16x32 A-fragment layout, contiguous 16B per (k8,m). Unchanged.
// ---------------------------------------------------------------------------
__global__ __launch_bounds__(256)
void modw_kernel(const float* __restrict__ style,
                 const float* __restrict__ weight,
                 __bf16* __restrict__ mw)
{
    const int id = blockIdx.x * 256 + threadIdx.x;   // 512 blocks x 256 thr
    const int k8 = id & 63;
    const int m  = (id >> 6) & 127;
    const int b  = id >> 13;

    const float4 w0 = *(const float4*)(weight + m * CIN + k8 * 8);
    const float4 w1 = *(const float4*)(weight + m * CIN + k8 * 8 + 4);
    const float4 s0 = *(const float4*)(style + b * CIN + k8 * 8);
    const float4 s1 = *(const float4*)(style + b * CIN + k8 * 8 + 4);

    union { unsigned short us[8]; bf16x8 v; } pk;
    pk.us[0] = f2bf_bits(w0.x * s0.x);
    pk.us[1] = f2bf_bits(w0.y * s0.y);
    pk.us[2] = f2bf_bits(w0.z * s0.z);
    pk.us[3] = f2bf_bits(w0.w * s0.w);
    pk.us[4] = f2bf_bits(w1.x * s1.x);
    pk.us[5] = f2bf_bits(w1.y * s1.y);
    pk.us[6] = f2bf_bits(w1.z * s1.z);
    pk.us[7] = f2bf_bits(w1.w * s1.w);
    *(bf16x8*)(mw + ((size_t)(b * 64 + k8) * 128 + m) * 8) = pk.v;
}

// ---------------------------------------------------------------------------
// Barrier-free, LDS-free streaming GEMM.
// Wave tile = 128(m) x 16(n): each x element loaded exactly once per block.
// B-fragment loaded directly from global (8 dwords, 4x64B segments/instr),
// A-fragment (mw) from L1/L2 (co-resident blocks share batch: b = bid & 15).
// 2-deep register double-buffer on the x stream; no __syncthreads anywhere.
// ---------------------------------------------------------------------------
__global__ __launch_bounds__(256, 4)
void modconv1x1_kernel(const float* __restrict__ x,
                       const __bf16* __restrict__ mw,
                       float* __restrict__ out)
{
    const int tid  = threadIdx.x;
    const int lane = tid & 63;
    const int wave = tid >> 6;      // 0..3
    const int quad = lane >> 4;     // 0..3  (k-slab within K-tile)
    const int l15  = lane & 15;     // n-col / m-row within fragment

    const int b  = blockIdx.x & 15;   // co-resident blocks (bid+256k) same batch
    const int nt = blockIdx.x >> 4;   // 0..63 n-tiles of 64
    const int n0 = nt * 64 + wave * 16;

    // x[b][k][n0+l15], fragment rows k = it*32 + quad*8 + j
    const float*  xb  = x + (size_t)b * CIN * HW + (size_t)quad * 8 * HW + n0 + l15;
    // mw[b][k8][m][j]: k8 = it*4 + quad, m = tm*16 + l15, 16B contiguous
    const __bf16* mwb = mw + (size_t)b * (64 * 128 * 8) + quad * (128 * 8) + l15 * 8;
    float*        outb = out + (size_t)b * COUT * HW + n0 + l15;

    floatx4 acc[8];
    #pragma unroll
    for (int tm = 0; tm < 8; ++tm) acc[tm] = (floatx4){0.f, 0.f, 0.f, 0.f};

    float xv0[8], xv1[8];   // explicit names: no runtime-indexed arrays

#define XLOAD(DST, IT)                                                        \
    _Pragma("unroll")                                                         \
    for (int j = 0; j < 8; ++j)                                               \
        DST[j] = xb[((size_t)(IT) * 32 + j) * HW];

#define BODY(IT, CUR, NXT, PRE)                                               \
    {                                                                         \
        if (PRE) { XLOAD(NXT, (IT) + 1) }                                     \
        const __bf16* ap = mwb + (size_t)(IT) * (4 * 128 * 8);                \
        bf16x8 af0[4], af1[4];                                                \
        _Pragma("unroll")                                                     \
        for (int tm = 0; tm < 4; ++tm)                                        \
            af0[tm] = *(const bf16x8*)(ap + tm * (16 * 8));                   \
        _Pragma("unroll")                                                     \
        for (int tm = 0; tm < 4; ++tm)                                        \
            af1[tm] = *(const bf16x8*)(ap + (4 + tm) * (16 * 8));             \
        union { unsigned short us[8]; bf16x8 v; } pk;                         \
        _Pragma("unroll")                                                     \
        for (int j = 0; j < 8; ++j) pk.us[j] = f2bf_bits(CUR[j]);             \
        _Pragma("unroll")                                                     \
        for (int tm = 0; tm < 4; ++tm)                                        \
            acc[tm] = __builtin_amdgcn_mfma_f32_16x16x32_bf16(                \
                af0[tm], pk.v, acc[tm], 0, 0, 0);                             \
        _Pragma("unroll")                                                     \
        for (int tm = 0; tm < 4; ++tm)                                        \
            acc[4 + tm] = __builtin_amdgcn_mfma_f32_16x16x32_bf16(            \
                af1[tm], pk.v, acc[4 + tm], 0, 0, 0);                         \
    }

    XLOAD(xv0, 0)
    #pragma unroll 1
    for (int it2 = 0; it2 < 8; ++it2) {
        const int it = it2 * 2;
        BODY(it,     xv0, xv1, 1)
        BODY(it + 1, xv1, xv0, (it2 < 7))
    }
#undef BODY
#undef XLOAD

    // epilogue: C/D layout col(n)=l15, row(o)=quad*4+reg
    #pragma unroll
    for (int tm = 0; tm < 8; ++tm) {
        const int o = tm * 16 + quad * 4;
        #pragma unroll
        for (int r = 0; r < 4; ++r)
            outb[(size_t)(o + r) * HW] = acc[tm][r];
    }
}

extern "C" void kernel_launch(void* const* d_in, const int* in_sizes, int n_in,
                              void* d_out, int out_size, void* d_ws, size_t ws_size,
                              hipStream_t stream) {
    const float* x      = (const float*)d_in[0];   // (16, 512, 64, 64) fp32
    const float* style  = (const float*)d_in[1];   // (16, 512) fp32
    const float* weight = (const float*)d_in[2];   // (128, 512) fp32
    float* out = (float*)d_out;                    // (16, 128, 64, 64) fp32
    __bf16* mw = (__bf16*)d_ws;                    // 2 MB modulated weights

    modw_kernel<<<dim3(512), dim3(256), 0, stream>>>(style, weight, mw);
    modconv1x1_kernel<<<dim3(NB * 64), dim3(256), 0, stream>>>(x, mw, out);
}

// Round 2
// 209.334 us; speedup vs baseline: 1.0458x; 1.0458x over previous
//
#include <hip/hip_runtime.h>
#include <stdint.h>

// B=16, CIN=512, COUT=128, H=W=64
#define NB    16
#define CIN   512
#define COUT  128
#define HW    4096
#define BN    128             // N-tile per block (512B row-chunks)
#define BK    32              // K-tile per iteration
#define NIT   (CIN / BK)      // 16
// grid = 16 b x 32 n-tiles = 512 blocks x 512 thr = 2 blocks/CU

using bf16x8  = __attribute__((ext_vector_type(8))) __bf16;
using floatx4 = __attribute__((ext_vector_type(4))) float;

// RNE float -> bf16 bits (proven R1-R5 of previous session)
__device__ __forceinline__ unsigned short f2bf_bits(float f) {
    union { float f; unsigned u; } v; v.f = f;
    return (unsigned short)((v.u + 0x7fffu + ((v.u >> 16) & 1u)) >> 16);
}

// async global->LDS, 16B/lane; LDS dest = wave-uniform base + lane*16,
// global address is per-lane.
#define GLD16(g, l)                                                            \
    __builtin_amdgcn_global_load_lds(                                          \
        (const __attribute__((address_space(1))) void*)(g),                    \
        (__attribute__((address_space(3))) void*)(l), 16, 0, 0)

// ---------------------------------------------------------------------------
// Precompute mw[b][k8][m][j] = bf16(weight[m][k8*8+j] * style[b][k8*8+j])
// = the 16x16x32 A-fragment layout, contiguous 8KB slab per K-tile.
// ---------------------------------------------------------------------------
__global__ __launch_bounds__(256)
void modw_kernel(const float* __restrict__ style,
                 const float* __restrict__ weight,
                 __bf16* __restrict__ mw)
{
    const int id = blockIdx.x * 256 + threadIdx.x;   // 512 blocks
    const int k8 = id & 63;
    const int m  = (id >> 6) & 127;
    const int b  = id >> 13;

    const float4 w0 = *(const float4*)(weight + m * CIN + k8 * 8);
    const float4 w1 = *(const float4*)(weight + m * CIN + k8 * 8 + 4);
    const float4 s0 = *(const float4*)(style + b * CIN + k8 * 8);
    const float4 s1 = *(const float4*)(style + b * CIN + k8 * 8 + 4);

    union { unsigned short us[8]; bf16x8 v; } pk;
    pk.us[0] = f2bf_bits(w0.x * s0.x);
    pk.us[1] = f2bf_bits(w0.y * s0.y);
    pk.us[2] = f2bf_bits(w0.z * s0.z);
    pk.us[3] = f2bf_bits(w0.w * s0.w);
    pk.us[4] = f2bf_bits(w1.x * s1.x);
    pk.us[5] = f2bf_bits(w1.y * s1.y);
    pk.us[6] = f2bf_bits(w1.z * s1.z);
    pk.us[7] = f2bf_bits(w1.w * s1.w);
    *(bf16x8*)(mw + ((size_t)(b * 64 + k8) * 128 + m) * 8) = pk.v;
}

// ---------------------------------------------------------------------------
// 128x128 block tile, 512 threads (8 waves of 64x32).
// TRIPLE-buffered LDS + raw s_barrier + counted s_waitcnt vmcnt(3):
// stage(it+1) stays in flight across the barrier (no vmcnt(0) drain in the
// main loop) -> HBM stays saturated instead of latency-bound per iter.
// ---------------------------------------------------------------------------
__global__ __launch_bounds__(512, 4)
void modconv1x1_kernel(const float* __restrict__ x,
                       const __bf16* __restrict__ mw,
                       float* __restrict__ out)
{
    __shared__ __align__(16) __bf16 Alds[3][4096];      // [k8][m][j]  3 x 8 KB
    __shared__ __align__(16) float  Blds[3][BK * BN];   // [k][n]      3 x 16 KB

    const int tid  = threadIdx.x;
    const int lane = tid & 63;
    const int wave = tid >> 6;          // 0..7
    const int quad = lane >> 4;
    const int l15  = lane & 15;

    const int b  = blockIdx.x >> 5;
    const int n0 = (blockIdx.x & 31) * BN;

    const char*  xbb  = (const char*)(x + (size_t)b * CIN * HW + n0);
    float*       outb = out + (size_t)b * COUT * HW + n0;
    const char*  mwb  = (const char*)mw + (size_t)b * (64 * 128 * 16);  // 128KB/batch

    const int wm = (wave & 1) * 64;     // wave tile 64(m) x 32(n)
    const int wn = (wave >> 1) * 32;

    // B GLD geometry: instr g covers rows 2g,2g+1 (512B each).
    const int brsel = lane >> 5;        // 0/1: which of the two rows
    const int bcol  = lane & 31;        // float4 column within row

    floatx4 acc[4][2];
    #pragma unroll
    for (int i = 0; i < 4; ++i)
        #pragma unroll
        for (int j = 0; j < 2; ++j)
            acc[i][j] = (floatx4){0.f, 0.f, 0.f, 0.f};

    // per-wave: 1 A-GLD + 2 B-GLD = exactly 3 vmcnt events per stage
#define STAGE(K0, BUF)                                                         \
    {                                                                          \
        const char* at = mwb + (size_t)(K0) * 256;                             \
        char*       al = (char*)&Alds[BUF][0];                                 \
        GLD16(at + wave * 1024 + lane * 16, al + wave * 1024);                 \
        char* bl = (char*)&Blds[BUF][0];                                       \
        _Pragma("unroll")                                                      \
        for (int g = 0; g < 2; ++g) {                                          \
            const int gi = wave * 2 + g;              /* 0..15 */              \
            const int r  = gi * 2 + brsel;            /* row 0..31 */          \
            GLD16(xbb + (size_t)((K0) + r) * (HW * 4) + bcol * 16,             \
                  bl + gi * 1024);                                             \
        }                                                                      \
    }

#define COMPUTE(BUF)                                                           \
    {                                                                          \
        bf16x8 af[4];                                                          \
        _Pragma("unroll")                                                      \
        for (int tm = 0; tm < 4; ++tm)                                         \
            af[tm] = *(const bf16x8*)&Alds[BUF][(quad * COUT + wm + tm * 16 + l15) * 8]; \
        bf16x8 bfr[2];                                                         \
        _Pragma("unroll")                                                      \
        for (int tn = 0; tn < 2; ++tn) {                                       \
            union { unsigned short us[8]; bf16x8 v; } pk;                      \
            _Pragma("unroll")                                                  \
            for (int j = 0; j < 8; ++j)                                        \
                pk.us[j] = f2bf_bits(Blds[BUF][(quad * 8 + j) * BN + wn + tn * 16 + l15]); \
            bfr[tn] = pk.v;                                                    \
        }                                                                      \
        _Pragma("unroll")                                                      \
        for (int tm = 0; tm < 4; ++tm)                                         \
            _Pragma("unroll")                                                  \
            for (int tn = 0; tn < 2; ++tn)                                     \
                acc[tm][tn] = __builtin_amdgcn_mfma_f32_16x16x32_bf16(         \
                    af[tm], bfr[tn], acc[tm][tn], 0, 0, 0);                    \
    }

    // prologue: tiles 0,1 -> slots 0,1 (6 loads in flight)
    STAGE(0, 0)
    STAGE(BK, 1)

    // main loop: at top of iter `it`, outstanding = stage(it) [oldest 3] +
    // stage(it+1) [3]. vmcnt(3) retires stage(it); stage(it+1) stays in
    // flight across the barrier. Then issue stage(it+2) into slot (it+2)%3
    // (same slot as it-1, whose reads finished before this barrier).
    int sc = 0;          // compute slot = it % 3
    int ss = 2;          // stage slot   = (it+2) % 3
    int k0 = 2 * BK;     // stage K-offset
    #pragma unroll 1
    for (int it = 0; it < NIT - 2; ++it) {
        asm volatile("s_waitcnt vmcnt(3)" ::: "memory");
        __builtin_amdgcn_s_barrier();
        STAGE(k0, ss)
        COMPUTE(sc)
        k0 += BK;
        sc = (sc == 2) ? 0 : sc + 1;
        ss = (ss == 2) ? 0 : ss + 1;
    }
    // it = 14: outstanding = stage(14)+stage(15); wait stage(14), no stage
    asm volatile("s_waitcnt vmcnt(3)" ::: "memory");
    __builtin_amdgcn_s_barrier();
    COMPUTE(2)           // 14 % 3
    // it = 15: drain stage(15)
    asm volatile("s_waitcnt vmcnt(0)" ::: "memory");
    __builtin_amdgcn_s_barrier();
    COMPUTE(0)           // 15 % 3
#undef STAGE
#undef COMPUTE

    // epilogue: C/D layout col(n)=l15, row(o)=quad*4+reg
    #pragma unroll
    for (int tm = 0; tm < 4; ++tm) {
        const int o = wm + tm * 16 + quad * 4;
        #pragma unroll
        for (int tn = 0; tn < 2; ++tn) {
            const int n = wn + tn * 16 + l15;
            #pragma unroll
            for (int r = 0; r < 4; ++r)
                outb[(size_t)(o + r) * HW + n] = acc[tm][tn][r];
        }
    }
}

extern "C" void kernel_launch(void* const* d_in, const int* in_sizes, int n_in,
                              void* d_out, int out_size, void* d_ws, size_t ws_size,
                              hipStream_t stream) {
    const float* x      = (const float*)d_in[0];   // (16, 512, 64, 64) fp32
    const float* style  = (const float*)d_in[1];   // (16, 512) fp32
    const float* weight = (const float*)d_in[2];   // (128, 512) fp32
    float* out = (float*)d_out;                    // (16, 128, 64, 64) fp32
    __bf16* mw = (__bf16*)d_ws;                    // 2 MB modulated weights

    modw_kernel<<<dim3(512), dim3(256), 0, stream>>>(style, weight, mw);
    modconv1x1_kernel<<<dim3(NB * 32), dim3(512), 0, stream>>>(x, mw, out);
}